// Round 3
// baseline (107.193 us; speedup 1.0000x reference)
//
#include <hip/hip_runtime.h>

#define S 128
#define LOG2E 1.4426950408889634f
#define LN2F  0.6931471805599453f

typedef float f4 __attribute__((ext_vector_type(4)));

static __device__ __forceinline__ float fexp2(float x) {
#if __has_builtin(__builtin_amdgcn_exp2f)
    return __builtin_amdgcn_exp2f(x);
#else
    return exp2f(x);
#endif
}
static __device__ __forceinline__ float flog2(float x) {
#if __has_builtin(__builtin_amdgcn_logf)
    return __builtin_amdgcn_logf(x);
#else
    return log2f(x);
#endif
}
// base-2 softplus: log2(1 + 2^x) = max(x,0) + log2(1 + 2^(-|x|))
static __device__ __forceinline__ float sp2(float x) {
    float a = fminf(x, -x);                 // -|x|
    float l = flog2(1.0f + fexp2(a));
    return fmaxf(x, 0.0f) + l;
}

// One block per (i, batch). 1024 threads: t -> row j = t>>3, k-group g = t&7,
// each thread streams 16 k-elements (4x float4), preloaded at kernel entry.
//
// Hat domain (scaled by log2e; output multiplies back by ln2):
//   db1[k] = mc[k]*(pe1[k]-pe0[k]);  Kd = sum db1;  N = sum mc
//   Crow[j] = sum_k mc[k]*sp2(sv[j,k])
//   db2[j] = mc[j]*(dpe[j] + Kd + Crow[j] - N)
//   d2[k]  = db2[k] - db1[k]                         (j-independent)
//   T0 = sum_k mc[k]*sp2(d2);  T1 = sum_k mc[k]*d2
//   out[j,0] = ln2*mc[j]*(pe0[j] - T0)
//   out[j,1] = ln2*mc[j]*(pe1[j] + T1 - T0)
__global__ __launch_bounds__(1024) void lbp_kernel(
    const float* __restrict__ s_edge,
    const float* __restrict__ s_sib,
    const unsigned char* __restrict__ mask_raw,
    float* __restrict__ out)
{
    const int i    = blockIdx.x & (S - 1);
    const int bb   = blockIdx.x >> 7;
    const int t    = threadIdx.x;
    const int j    = t >> 3;
    const int g    = t & 3 | (t & 7);   // (kept simple below)
    const int gg   = t & 7;
    const int wid  = t >> 6;
    const int lane = t & 63;

    __shared__ __align__(16) float s_mc[S];
    __shared__ __align__(16) float s_pe0[S];
    __shared__ __align__(16) float s_pe1[S];
    __shared__ __align__(16) float s_db1[S];
    __shared__ __align__(16) float s_db2[S];
    __shared__ float s_Kd, s_N;
    __shared__ int s_wf[16];

    // ---- issue the streaming s_sib loads FIRST (depend on nothing) ----
    const f4* __restrict__ srow = (const f4*)(s_sib + ((bb * S + j) * S + i) * S);
    const f4 sv0 = __builtin_nontemporal_load(srow + gg);
    const f4 sv1 = __builtin_nontemporal_load(srow + 8  + gg);
    const f4 sv2 = __builtin_nontemporal_load(srow + 16 + gg);
    const f4 sv3 = __builtin_nontemporal_load(srow + 24 + gg);

    // ---- mask dtype detect over first 4KB: one flag per wave, no atomics ----
    // bool8: nonzero bytes at %4!=0; int32(0/1): only %4==0 nonzero; f32: %4==3 byte 0x3F.
    {
        uchar4 v = ((const uchar4*)mask_raw)[t];
        int a1 = __any((v.y | v.z | v.w) != 0) ? 1 : 0;
        int a2 = __any(v.w == 0x3F) ? 2 : 0;
        if (lane == 0) s_wf[wid] = a1 | a2;
    }
    __syncthreads();                                           // (1)

    // ---- phase 0: mask column, scaled p_edge column, db1 ----
    if (t < S) {
        int flag = 0;
        #pragma unroll
        for (int w = 0; w < 16; ++w) flag |= s_wf[w];
        const int mode = (flag & 2) ? 2 : ((flag & 1) ? 0 : 1); // 2=f32,0=bool8,1=int32
        const int midx = (bb * S + t) * S + i;
        int mval;
        if (mode == 0)      mval = mask_raw[midx];
        else if (mode == 1) mval = ((const int*)mask_raw)[midx];
        else                mval = (((const float*)mask_raw)[midx] != 0.0f);
        const float mc  = mval ? 1.0f : 0.0f;
        const float pe0 = s_edge[midx * 2]     * LOG2E;
        const float pe1 = s_edge[midx * 2 + 1] * LOG2E;
        s_mc[t]  = mc;
        s_pe0[t] = pe0;
        s_pe1[t] = pe1;
        s_db1[t] = mc * (pe1 - pe0);
    }
    __syncthreads();                                           // (2)

    // wave 0: Kd = sum(db1), N = sum(mc)  (runs while others start Crow)
    if (wid == 0) {
        float kd = s_db1[lane] + s_db1[lane + 64];
        float nn = s_mc[lane]  + s_mc[lane + 64];
        #pragma unroll
        for (int o = 1; o < 64; o <<= 1) {
            kd += __shfl_xor(kd, o);
            nn += __shfl_xor(nn, o);
        }
        if (lane == 0) { s_Kd = kd; s_N = nn; }
    }

    // ---- Crow[j] from preloaded registers ----
    float acc = 0.0f;
    {
        const f4 m0 = *(const f4*)(s_mc + 4 * gg);
        const f4 m1 = *(const f4*)(s_mc + 32 + 4 * gg);
        const f4 m2 = *(const f4*)(s_mc + 64 + 4 * gg);
        const f4 m3 = *(const f4*)(s_mc + 96 + 4 * gg);
        acc = fmaf(m0.x, sp2(LOG2E * sv0.x), acc);
        acc = fmaf(m0.y, sp2(LOG2E * sv0.y), acc);
        acc = fmaf(m0.z, sp2(LOG2E * sv0.z), acc);
        acc = fmaf(m0.w, sp2(LOG2E * sv0.w), acc);
        acc = fmaf(m1.x, sp2(LOG2E * sv1.x), acc);
        acc = fmaf(m1.y, sp2(LOG2E * sv1.y), acc);
        acc = fmaf(m1.z, sp2(LOG2E * sv1.z), acc);
        acc = fmaf(m1.w, sp2(LOG2E * sv1.w), acc);
        acc = fmaf(m2.x, sp2(LOG2E * sv2.x), acc);
        acc = fmaf(m2.y, sp2(LOG2E * sv2.y), acc);
        acc = fmaf(m2.z, sp2(LOG2E * sv2.z), acc);
        acc = fmaf(m2.w, sp2(LOG2E * sv2.w), acc);
        acc = fmaf(m3.x, sp2(LOG2E * sv3.x), acc);
        acc = fmaf(m3.y, sp2(LOG2E * sv3.y), acc);
        acc = fmaf(m3.z, sp2(LOG2E * sv3.z), acc);
        acc = fmaf(m3.w, sp2(LOG2E * sv3.w), acc);
    }
    acc += __shfl_xor(acc, 1);
    acc += __shfl_xor(acc, 2);
    acc += __shfl_xor(acc, 4);
    __syncthreads();                                           // (3) s_Kd/s_N ready

    if (gg == 0) {
        const float mcj = s_mc[j];
        s_db2[j] = mcj * ((s_pe1[j] - s_pe0[j]) + s_Kd + acc - s_N);
    }
    __syncthreads();                                           // (4)

    // ---- wave 0 tail: T0/T1 then both output rows per lane ----
    if (wid == 0) {
        const float mcA = s_mc[lane], mcB = s_mc[lane + 64];
        const float dA  = s_db2[lane]      - s_db1[lane];
        const float dB  = s_db2[lane + 64] - s_db1[lane + 64];
        float a0 = fmaf(mcA, sp2(dA), mcB * sp2(dB));
        float a1 = fmaf(mcA, dA, mcB * dB);
        #pragma unroll
        for (int o = 1; o < 64; o <<= 1) {
            a0 += __shfl_xor(a0, o);
            a1 += __shfl_xor(a1, o);
        }
        const int base = (bb * S) * S + i;
        {
            const float mc = mcA;
            const float o0 = LN2F * mc * (s_pe0[lane] - a0);
            const float o1 = LN2F * mc * (s_pe1[lane] + a1 - a0);
            *(float2*)(out + (base + lane * S) * 2) = make_float2(o0, o1);
        }
        {
            const float mc = mcB;
            const float o0 = LN2F * mc * (s_pe0[lane + 64] - a0);
            const float o1 = LN2F * mc * (s_pe1[lane + 64] + a1 - a0);
            *(float2*)(out + (base + (lane + 64) * S) * 2) = make_float2(o0, o1);
        }
    }
}

extern "C" void kernel_launch(void* const* d_in, const int* in_sizes, int n_in,
                              void* d_out, int out_size, void* d_ws, size_t ws_size,
                              hipStream_t stream) {
    const float* s_edge = (const float*)d_in[0];
    const float* s_sib  = (const float*)d_in[1];
    const unsigned char* mask = (const unsigned char*)d_in[2];
    float* out = (float*)d_out;

    const int B = in_sizes[0] / (S * S * 2);   // 8
    lbp_kernel<<<dim3(B * S), dim3(1024), 0, stream>>>(s_edge, s_sib, mask, out);
}

// Round 4
// 106.319 us; speedup vs baseline: 1.0082x; 1.0082x over previous
//
#include <hip/hip_runtime.h>

#define S 128
#define LOG2E 1.4426950408889634f
#define LN2F  0.6931471805599453f

typedef float f4 __attribute__((ext_vector_type(4)));

static __device__ __forceinline__ float fexp2(float x) {
#if __has_builtin(__builtin_amdgcn_exp2f)
    return __builtin_amdgcn_exp2f(x);
#else
    return exp2f(x);
#endif
}
static __device__ __forceinline__ float flog2(float x) {
#if __has_builtin(__builtin_amdgcn_logf)
    return __builtin_amdgcn_logf(x);
#else
    return log2f(x);
#endif
}
// base-2 softplus: log2(1 + 2^x) = max(x,0) + log2(1 + 2^(-|x|))
static __device__ __forceinline__ float sp2(float x) {
    float a = fminf(x, -x);                 // -|x|
    float l = flog2(1.0f + fexp2(a));
    return fmaxf(x, 0.0f) + l;
}

// One block per (i, batch). 1024 threads: t -> row j = t>>3, k-group gg = t&7.
// Loads are issued INSIDE the Crow loop (short VGPR live ranges -> <=64 VGPR
// -> 2 blocks/CU so the phase-0 gather latency hides under the other block's
// streaming; R3's entry-preload broke this and regressed).
//
// Hat domain (scaled by log2e; output multiplies back by ln2):
//   db1[k] = mc[k]*(pe1[k]-pe0[k]);  Kd = sum db1;  N = sum mc
//   Crow[j] = sum_k mc[k]*sp2(sv[j,k])
//   db2[j] = mc[j]*(dpe[j] + Kd + Crow[j] - N)
//   d2[k]  = db2[k] - db1[k]                         (j-independent)
//   T0 = sum_k mc[k]*sp2(d2);  T1 = sum_k mc[k]*d2
//   out[j,0] = ln2*mc[j]*(pe0[j] - T0)
//   out[j,1] = ln2*mc[j]*(pe1[j] + T1 - T0)
__global__ __launch_bounds__(1024) void lbp_kernel(
    const float* __restrict__ s_edge,
    const float* __restrict__ s_sib,
    const unsigned char* __restrict__ mask_raw,
    float* __restrict__ out)
{
    const int i    = blockIdx.x & (S - 1);
    const int bb   = blockIdx.x >> 7;
    const int t    = threadIdx.x;
    const int j    = t >> 3;
    const int gg   = t & 7;
    const int wid  = t >> 6;
    const int lane = t & 63;

    __shared__ __align__(16) float s_mc[S];
    __shared__ __align__(16) float s_pe0[S];
    __shared__ __align__(16) float s_pe1[S];
    __shared__ __align__(16) float s_db1[S];
    __shared__ __align__(16) float s_db2[S];
    __shared__ float s_Kd, s_N;
    __shared__ int s_wf[16];

    // ---- mask dtype detect over first 4KB: one ballot flag per wave ----
    // bool8: nonzero bytes at %4!=0; int32(0/1): only %4==0 nonzero; f32: %4==3 byte 0x3F.
    {
        uchar4 v = ((const uchar4*)mask_raw)[t];
        int a1 = __any((v.y | v.z | v.w) != 0) ? 1 : 0;
        int a2 = __any(v.w == 0x3F) ? 2 : 0;
        if (lane == 0) s_wf[wid] = a1 | a2;
    }
    __syncthreads();                                           // (1)

    // ---- phase 0: mask column, scaled p_edge column, db1 ----
    if (t < S) {
        int flag = 0;
        #pragma unroll
        for (int w = 0; w < 16; ++w) flag |= s_wf[w];
        const int mode = (flag & 2) ? 2 : ((flag & 1) ? 0 : 1); // 2=f32,0=bool8,1=int32
        const int midx = (bb * S + t) * S + i;
        int mval;
        if (mode == 0)      mval = mask_raw[midx];
        else if (mode == 1) mval = ((const int*)mask_raw)[midx];
        else                mval = (((const float*)mask_raw)[midx] != 0.0f);
        const float mc  = mval ? 1.0f : 0.0f;
        const float pe0 = s_edge[midx * 2]     * LOG2E;
        const float pe1 = s_edge[midx * 2 + 1] * LOG2E;
        s_mc[t]  = mc;
        s_pe0[t] = pe0;
        s_pe1[t] = pe1;
        s_db1[t] = mc * (pe1 - pe0);
    }
    __syncthreads();                                           // (2)

    // wave 0: Kd = sum(db1), N = sum(mc)  (overlaps other waves' Crow start)
    if (wid == 0) {
        float kd = s_db1[lane] + s_db1[lane + 64];
        float nn = s_mc[lane]  + s_mc[lane + 64];
        #pragma unroll
        for (int o = 1; o < 64; o <<= 1) {
            kd += __shfl_xor(kd, o);
            nn += __shfl_xor(nn, o);
        }
        if (lane == 0) { s_Kd = kd; s_N = nn; }
    }

    // ---- Crow[j]: stream 16 k-elements, loads in-loop (compiler pipelines) ----
    float acc = 0.0f;
    const f4* __restrict__ srow = (const f4*)(s_sib + ((bb * S + j) * S + i) * S);
    #pragma unroll
    for (int r = 0; r < 4; ++r) {
        const f4 sv = __builtin_nontemporal_load(srow + r * 8 + gg);  // nt: keep mask/pe L2-resident
        const f4 m  = *(const f4*)(s_mc + r * 32 + 4 * gg);
        acc = fmaf(m.x, sp2(LOG2E * sv.x), acc);
        acc = fmaf(m.y, sp2(LOG2E * sv.y), acc);
        acc = fmaf(m.z, sp2(LOG2E * sv.z), acc);
        acc = fmaf(m.w, sp2(LOG2E * sv.w), acc);
    }
    acc += __shfl_xor(acc, 1);
    acc += __shfl_xor(acc, 2);
    acc += __shfl_xor(acc, 4);
    __syncthreads();                                           // (3) s_Kd/s_N ready

    if (gg == 0) {
        const float mcj = s_mc[j];
        s_db2[j] = mcj * ((s_pe1[j] - s_pe0[j]) + s_Kd + acc - s_N);
    }
    __syncthreads();                                           // (4)

    // ---- wave 0 tail: T0/T1 then both output rows per lane ----
    if (wid == 0) {
        const float mcA = s_mc[lane], mcB = s_mc[lane + 64];
        const float dA  = s_db2[lane]      - s_db1[lane];
        const float dB  = s_db2[lane + 64] - s_db1[lane + 64];
        float a0 = fmaf(mcA, sp2(dA), mcB * sp2(dB));
        float a1 = fmaf(mcA, dA, mcB * dB);
        #pragma unroll
        for (int o = 1; o < 64; o <<= 1) {
            a0 += __shfl_xor(a0, o);
            a1 += __shfl_xor(a1, o);
        }
        const int base = (bb * S) * S + i;
        {
            const float o0 = LN2F * mcA * (s_pe0[lane] - a0);
            const float o1 = LN2F * mcA * (s_pe1[lane] + a1 - a0);
            *(float2*)(out + (base + lane * S) * 2) = make_float2(o0, o1);
        }
        {
            const float o0 = LN2F * mcB * (s_pe0[lane + 64] - a0);
            const float o1 = LN2F * mcB * (s_pe1[lane + 64] + a1 - a0);
            *(float2*)(out + (base + (lane + 64) * S) * 2) = make_float2(o0, o1);
        }
    }
}

extern "C" void kernel_launch(void* const* d_in, const int* in_sizes, int n_in,
                              void* d_out, int out_size, void* d_ws, size_t ws_size,
                              hipStream_t stream) {
    const float* s_edge = (const float*)d_in[0];
    const float* s_sib  = (const float*)d_in[1];
    const unsigned char* mask = (const unsigned char*)d_in[2];
    float* out = (float*)d_out;

    const int B = in_sizes[0] / (S * S * 2);   // 8
    lbp_kernel<<<dim3(B * S), dim3(1024), 0, stream>>>(s_edge, s_sib, mask, out);
}

// Round 6
// 99.948 us; speedup vs baseline: 1.0725x; 1.0637x over previous
//
#include <hip/hip_runtime.h>

#define S 128
#define LOG2E 1.4426950408889634f
#define LN2F  0.6931471805599453f

typedef float f4 __attribute__((ext_vector_type(4)));

static __device__ __forceinline__ float fexp2(float x) {
#if __has_builtin(__builtin_amdgcn_exp2f)
    return __builtin_amdgcn_exp2f(x);
#else
    return exp2f(x);
#endif
}
static __device__ __forceinline__ float flog2(float x) {
#if __has_builtin(__builtin_amdgcn_logf)
    return __builtin_amdgcn_logf(x);
#else
    return log2f(x);
#endif
}
// base-2 softplus: log2(1 + 2^x) = max(x,0) + log2(1 + 2^(-|x|))
static __device__ __forceinline__ float sp2(float x) {
    float a = fminf(x, -x);                 // -|x|
    float l = flog2(1.0f + fexp2(a));
    return fmaxf(x, 0.0f) + l;
}

// One block per (i, batch). 1024 threads: t -> row j = t>>3, k-group gg = t&7.
// Plain (cached) loads in the Crow loop — NT hint was the R3/R4 regression
// (no reuse benefit to offset whatever allocation-policy cost it incurs).
//
// Hat domain (scaled by log2e; output multiplies back by ln2):
//   db1[k] = mc[k]*(pe1[k]-pe0[k]);  Kd = sum db1;  N = sum mc
//   Crow[j] = sum_k mc[k]*sp2(sv[j,k])
//   db2[j] = mc[j]*(dpe[j] + Kd + Crow[j] - N)
//   d2[k]  = db2[k] - db1[k]                         (j-independent)
//   T0 = sum_k mc[k]*sp2(d2);  T1 = sum_k mc[k]*d2
//   out[j,0] = ln2*mc[j]*(pe0[j] - T0)
//   out[j,1] = ln2*mc[j]*(pe1[j] + T1 - T0)
__global__ __launch_bounds__(1024) void lbp_kernel(
    const float* __restrict__ s_edge,
    const float* __restrict__ s_sib,
    const unsigned char* __restrict__ mask_raw,
    float* __restrict__ out)
{
    const int i    = blockIdx.x & (S - 1);
    const int bb   = blockIdx.x >> 7;
    const int t    = threadIdx.x;
    const int j    = t >> 3;
    const int gg   = t & 7;
    const int wid  = t >> 6;
    const int lane = t & 63;

    __shared__ __align__(16) float s_mc[S];
    __shared__ __align__(16) float s_pe0[S];
    __shared__ __align__(16) float s_pe1[S];
    __shared__ __align__(16) float s_db1[S];
    __shared__ __align__(16) float s_db2[S];
    __shared__ float s_Kd, s_N;
    __shared__ int s_wf[16];

    // ---- mask dtype detect over first 4KB: one ballot flag per wave ----
    // bool8: nonzero bytes at %4!=0; int32(0/1): only %4==0 nonzero; f32: %4==3 byte 0x3F.
    {
        uchar4 v = ((const uchar4*)mask_raw)[t];
        int a1 = __any((v.y | v.z | v.w) != 0) ? 1 : 0;
        int a2 = __any(v.w == 0x3F) ? 2 : 0;
        if (lane == 0) s_wf[wid] = a1 | a2;
    }
    __syncthreads();                                           // (1)

    // ---- phase 0: mask column, scaled p_edge column, db1 ----
    if (t < S) {
        int flag = 0;
        #pragma unroll
        for (int w = 0; w < 16; ++w) flag |= s_wf[w];
        const int mode = (flag & 2) ? 2 : ((flag & 1) ? 0 : 1); // 2=f32,0=bool8,1=int32
        const int midx = (bb * S + t) * S + i;
        int mval;
        if (mode == 0)      mval = mask_raw[midx];
        else if (mode == 1) mval = ((const int*)mask_raw)[midx];
        else                mval = (((const float*)mask_raw)[midx] != 0.0f);
        const float mc  = mval ? 1.0f : 0.0f;
        const float pe0 = s_edge[midx * 2]     * LOG2E;
        const float pe1 = s_edge[midx * 2 + 1] * LOG2E;
        s_mc[t]  = mc;
        s_pe0[t] = pe0;
        s_pe1[t] = pe1;
        s_db1[t] = mc * (pe1 - pe0);
    }
    __syncthreads();                                           // (2)

    // wave 0: Kd = sum(db1), N = sum(mc)  (overlaps other waves' Crow start)
    if (wid == 0) {
        float kd = s_db1[lane] + s_db1[lane + 64];
        float nn = s_mc[lane]  + s_mc[lane + 64];
        #pragma unroll
        for (int o = 1; o < 64; o <<= 1) {
            kd += __shfl_xor(kd, o);
            nn += __shfl_xor(nn, o);
        }
        if (lane == 0) { s_Kd = kd; s_N = nn; }
    }

    // ---- Crow[j]: stream 16 k-elements (4x float4, plain cached loads) ----
    float acc = 0.0f;
    const f4* __restrict__ srow = (const f4*)(s_sib + ((bb * S + j) * S + i) * S);
    #pragma unroll
    for (int r = 0; r < 4; ++r) {
        const f4 sv = srow[r * 8 + gg];
        const f4 m  = *(const f4*)(s_mc + r * 32 + 4 * gg);
        acc = fmaf(m.x, sp2(LOG2E * sv.x), acc);
        acc = fmaf(m.y, sp2(LOG2E * sv.y), acc);
        acc = fmaf(m.z, sp2(LOG2E * sv.z), acc);
        acc = fmaf(m.w, sp2(LOG2E * sv.w), acc);
    }
    acc += __shfl_xor(acc, 1);
    acc += __shfl_xor(acc, 2);
    acc += __shfl_xor(acc, 4);
    __syncthreads();                                           // (3) s_Kd/s_N ready

    if (gg == 0) {
        const float mcj = s_mc[j];
        s_db2[j] = mcj * ((s_pe1[j] - s_pe0[j]) + s_Kd + acc - s_N);
    }
    __syncthreads();                                           // (4)

    // ---- wave 0 tail: T0/T1 then both output rows per lane ----
    if (wid == 0) {
        const float mcA = s_mc[lane], mcB = s_mc[lane + 64];
        const float dA  = s_db2[lane]      - s_db1[lane];
        const float dB  = s_db2[lane + 64] - s_db1[lane + 64];
        float a0 = fmaf(mcA, sp2(dA), mcB * sp2(dB));
        float a1 = fmaf(mcA, dA, mcB * dB);
        #pragma unroll
        for (int o = 1; o < 64; o <<= 1) {
            a0 += __shfl_xor(a0, o);
            a1 += __shfl_xor(a1, o);
        }
        const int base = (bb * S) * S + i;
        {
            const float o0 = LN2F * mcA * (s_pe0[lane] - a0);
            const float o1 = LN2F * mcA * (s_pe1[lane] + a1 - a0);
            *(float2*)(out + (base + lane * S) * 2) = make_float2(o0, o1);
        }
        {
            const float o0 = LN2F * mcB * (s_pe0[lane + 64] - a0);
            const float o1 = LN2F * mcB * (s_pe1[lane + 64] + a1 - a0);
            *(float2*)(out + (base + (lane + 64) * S) * 2) = make_float2(o0, o1);
        }
    }
}

extern "C" void kernel_launch(void* const* d_in, const int* in_sizes, int n_in,
                              void* d_out, int out_size, void* d_ws, size_t ws_size,
                              hipStream_t stream) {
    const float* s_edge = (const float*)d_in[0];
    const float* s_sib  = (const float*)d_in[1];
    const unsigned char* mask = (const unsigned char*)d_in[2];
    float* out = (float*)d_out;

    const int B = in_sizes[0] / (S * S * 2);   // 8
    lbp_kernel<<<dim3(B * S), dim3(1024), 0, stream>>>(s_edge, s_sib, mask, out);
}

// Round 7
// 99.801 us; speedup vs baseline: 1.0741x; 1.0015x over previous
//
#include <hip/hip_runtime.h>

#define S 128
#define LOG2E 1.4426950408889634f
#define LN2F  0.6931471805599453f

typedef float f4 __attribute__((ext_vector_type(4)));

static __device__ __forceinline__ float fexp2(float x) {
#if __has_builtin(__builtin_amdgcn_exp2f)
    return __builtin_amdgcn_exp2f(x);
#else
    return exp2f(x);
#endif
}
static __device__ __forceinline__ float flog2(float x) {
#if __has_builtin(__builtin_amdgcn_logf)
    return __builtin_amdgcn_logf(x);
#else
    return log2f(x);
#endif
}
// base-2 softplus: log2(1 + 2^x) = max(x,0) + log2(1 + 2^(-|x|))
static __device__ __forceinline__ float sp2(float x) {
    float a = fminf(x, -x);                 // -|x|
    float l = flog2(1.0f + fexp2(a));
    return fmaxf(x, 0.0f) + l;
}

// One block per (batch, i-pair): processes columns i0 and i0+1. Grid = B*64 =
// 512 blocks = exactly 2 resident blocks x 256 CU (single round, no sequential
// block rounds). For fixed (b,j) the two columns' s_sib rows are contiguous
// (256 floats), so streaming reads 1KB-contiguous per (b,j).
//
// Hat domain per column c (scaled by log2e; output multiplies back by ln2):
//   db1[k] = mc[k]*(pe1[k]-pe0[k]);  Kd = sum db1;  N = sum mc
//   Crow[j] = sum_k mc[k]*sp2(sv[j,k])
//   db2[j] = mc[j]*(dpe[j] + Kd + Crow[j] - N)
//   d2[k]  = db2[k] - db1[k]                         (j-independent)
//   T0 = sum_k mc[k]*sp2(d2);  T1 = sum_k mc[k]*d2
//   out[j,0] = ln2*mc[j]*(pe0[j] - T0)
//   out[j,1] = ln2*mc[j]*(pe1[j] + T1 - T0)
__global__ __launch_bounds__(1024, 8) void lbp_kernel(
    const float* __restrict__ s_edge,
    const float* __restrict__ s_sib,
    const unsigned char* __restrict__ mask_raw,
    float* __restrict__ out)
{
    const int iPair = blockIdx.x & 63;
    const int bb    = blockIdx.x >> 6;
    const int i0    = iPair * 2;
    const int t     = threadIdx.x;
    const int j     = t >> 3;
    const int gg    = t & 7;
    const int wid   = t >> 6;
    const int lane  = t & 63;

    __shared__ __align__(16) float s_mc [2][S];
    __shared__ __align__(16) float s_pe0[2][S];
    __shared__ __align__(16) float s_pe1[2][S];
    __shared__ __align__(16) float s_db1[2][S];
    __shared__ __align__(16) float s_db2[2][S];
    __shared__ float s_Kd[2], s_N[2];
    __shared__ int s_wf[16];

    // ---- mask dtype detect over first 4KB: one ballot flag per wave ----
    // bool8: nonzero bytes at %4!=0; int32(0/1): only %4==0 nonzero; f32: %4==3 byte 0x3F.
    {
        uchar4 v = ((const uchar4*)mask_raw)[t];
        int a1 = __any((v.y | v.z | v.w) != 0) ? 1 : 0;
        int a2 = __any(v.w == 0x3F) ? 2 : 0;
        if (lane == 0) s_wf[wid] = a1 | a2;
    }
    __syncthreads();                                           // (1)

    // ---- phase 0: both mask columns, scaled p_edge columns, db1 ----
    if (t < 2 * S) {
        const int c  = t >> 7;          // column 0/1
        const int jj = t & (S - 1);
        int flag = 0;
        #pragma unroll
        for (int w = 0; w < 16; ++w) flag |= s_wf[w];
        const int mode = (flag & 2) ? 2 : ((flag & 1) ? 0 : 1); // 2=f32,0=bool8,1=int32
        const int midx = (bb * S + jj) * S + i0 + c;
        int mval;
        if (mode == 0)      mval = mask_raw[midx];
        else if (mode == 1) mval = ((const int*)mask_raw)[midx];
        else                mval = (((const float*)mask_raw)[midx] != 0.0f);
        const float mc  = mval ? 1.0f : 0.0f;
        const float pe0 = s_edge[midx * 2]     * LOG2E;
        const float pe1 = s_edge[midx * 2 + 1] * LOG2E;
        s_mc [c][jj] = mc;
        s_pe0[c][jj] = pe0;
        s_pe1[c][jj] = pe1;
        s_db1[c][jj] = mc * (pe1 - pe0);
    }
    __syncthreads();                                           // (2)

    // waves 0,1: Kd/N for their column (overlaps other waves' Crow start)
    if (wid < 2) {
        float kd = s_db1[wid][lane] + s_db1[wid][lane + 64];
        float nn = s_mc [wid][lane] + s_mc [wid][lane + 64];
        #pragma unroll
        for (int o = 1; o < 64; o <<= 1) {
            kd += __shfl_xor(kd, o);
            nn += __shfl_xor(nn, o);
        }
        if (lane == 0) { s_Kd[wid] = kd; s_N[wid] = nn; }
    }

    // ---- Crow[j] for both columns: 32 k-elements (8x float4, contiguous 1KB/row) ----
    float acc0 = 0.0f, acc1 = 0.0f;
    const f4* __restrict__ srow = (const f4*)(s_sib + ((bb * S + j) * S + i0) * S);
    #pragma unroll
    for (int r = 0; r < 4; ++r) {
        const f4 sv0 = srow[r * 8 + gg];            // column i0
        const f4 sv1 = srow[32 + r * 8 + gg];       // column i0+1
        const f4 m0  = *(const f4*)(&s_mc[0][r * 32 + 4 * gg]);
        const f4 m1  = *(const f4*)(&s_mc[1][r * 32 + 4 * gg]);
        acc0 = fmaf(m0.x, sp2(LOG2E * sv0.x), acc0);
        acc0 = fmaf(m0.y, sp2(LOG2E * sv0.y), acc0);
        acc0 = fmaf(m0.z, sp2(LOG2E * sv0.z), acc0);
        acc0 = fmaf(m0.w, sp2(LOG2E * sv0.w), acc0);
        acc1 = fmaf(m1.x, sp2(LOG2E * sv1.x), acc1);
        acc1 = fmaf(m1.y, sp2(LOG2E * sv1.y), acc1);
        acc1 = fmaf(m1.z, sp2(LOG2E * sv1.z), acc1);
        acc1 = fmaf(m1.w, sp2(LOG2E * sv1.w), acc1);
    }
    acc0 += __shfl_xor(acc0, 1); acc1 += __shfl_xor(acc1, 1);
    acc0 += __shfl_xor(acc0, 2); acc1 += __shfl_xor(acc1, 2);
    acc0 += __shfl_xor(acc0, 4); acc1 += __shfl_xor(acc1, 4);
    __syncthreads();                                           // (3) Kd/N ready

    if (gg == 0) {
        const float mcj = s_mc[0][j];
        s_db2[0][j] = mcj * ((s_pe1[0][j] - s_pe0[0][j]) + s_Kd[0] + acc0 - s_N[0]);
    }
    if (gg == 1) {
        const float mcj = s_mc[1][j];
        s_db2[1][j] = mcj * ((s_pe1[1][j] - s_pe0[1][j]) + s_Kd[1] + acc1 - s_N[1]);
    }
    __syncthreads();                                           // (4)

    // ---- waves 0,1 tail: T0/T1 then both output rows per lane, per column ----
    if (wid < 2) {
        const int c = wid;
        const float mcA = s_mc[c][lane], mcB = s_mc[c][lane + 64];
        const float dA  = s_db2[c][lane]      - s_db1[c][lane];
        const float dB  = s_db2[c][lane + 64] - s_db1[c][lane + 64];
        float a0 = fmaf(mcA, sp2(dA), mcB * sp2(dB));
        float a1 = fmaf(mcA, dA, mcB * dB);
        #pragma unroll
        for (int o = 1; o < 64; o <<= 1) {
            a0 += __shfl_xor(a0, o);
            a1 += __shfl_xor(a1, o);
        }
        const int base = (bb * S) * S + i0 + c;
        {
            const float o0 = LN2F * mcA * (s_pe0[c][lane] - a0);
            const float o1 = LN2F * mcA * (s_pe1[c][lane] + a1 - a0);
            *(float2*)(out + (base + lane * S) * 2) = make_float2(o0, o1);
        }
        {
            const float o0 = LN2F * mcB * (s_pe0[c][lane + 64] - a0);
            const float o1 = LN2F * mcB * (s_pe1[c][lane + 64] + a1 - a0);
            *(float2*)(out + (base + (lane + 64) * S) * 2) = make_float2(o0, o1);
        }
    }
}

extern "C" void kernel_launch(void* const* d_in, const int* in_sizes, int n_in,
                              void* d_out, int out_size, void* d_ws, size_t ws_size,
                              hipStream_t stream) {
    const float* s_edge = (const float*)d_in[0];
    const float* s_sib  = (const float*)d_in[1];
    const unsigned char* mask = (const unsigned char*)d_in[2];
    float* out = (float*)d_out;

    const int B = in_sizes[0] / (S * S * 2);   // 8
    lbp_kernel<<<dim3(B * 64), dim3(1024), 0, stream>>>(s_edge, s_sib, mask, out);
}